// Round 7
// baseline (175.534 us; speedup 1.0000x reference)
//
#include <hip/hip_runtime.h>

// R7 — DIAGNOSTIC ROUND (deliberately slow; reverts next round).
//
// Problem: all our dispatches are < 40us, below the rocprof top-5 cutoff
// (which is saturated by ~40us 256MiB workspace-poison fills), so six rounds
// of structural changes were steered by cycle models that were each 3-10x
// wrong. This round keeps R0's EXACT verified 3-node structure/bodies but
// repeats each body in-kernel — hist x64, scatter x32, query x8 — so each
// kernel's duration rises above the cutoff and appears in the counters.
// Per-rep duration = row_dur / reps.
//
// Idempotency: hist is pure recompute; scatter re-derives identical bases
// each rep and writes a complete valid within-cell permutation per rep
// (__syncthreads drains vmcnt, ordering reps, so final state = last rep's
// permutation — within-cell order is arbitrary by design, the query bitmap
// restores original-index order); query is deterministic. Output exact.
// An asm-opaque zero offset (z0) per rep prevents the compiler hoisting
// loads out of the rep loop (keeps per-rep work faithful).
//
// Ledger: R0 3-node = 68.2 (best). R4 proves fill+fixed = 44.2, so R0's
// pipeline (3 kernels + 2 boundaries) = ~24us — this round splits that 24.
// Decision tree for R8: Q>=10 -> optimize query; H+S>=8 -> memset+atomic-
// scatter build; all small -> revert to R0, declare structural floor.

constexpr int   K    = 64;
constexpr float R2   = 0.01f;   // 0.1^2
constexpr int   B    = 4;
constexpr int   N1   = 2048;
constexpr int   N2   = 8192;
constexpr int   GC   = 5;                 // grid cells per dim
constexpr int   NCELL = GC * GC * GC;     // 125
constexpr float INVCELL = 5.0f;           // 1 / 0.2
constexpr int   SUBS       = 128;         // 256-key sub-blocks total
constexpr int   SUBS_PER_B = 32;          // per batch

constexpr int   HREP = 64;                // hist reps     (expect ~64*H us)
constexpr int   SREP = 32;                // scatter reps  (expect ~32*S us)
constexpr int   QREP = 8;                 // query reps    (expect ~8*Q us)

// ---------------- workspace layout (identical to R0) ----------------
constexpr size_t SORTED_BYTES = (size_t)B * N2 * 16;
constexpr size_t CS_BYTES     = (size_t)B * (NCELL + 1) * 4;
constexpr size_t WS_NEEDED    = SORTED_BYTES + CS_BYTES + (size_t)SUBS * NCELL * 4;

__device__ __forceinline__ int cell_of(float v) {
    int c = (int)(v * INVCELL);
    return c < 0 ? 0 : (c > GC - 1 ? GC - 1 : c);
}

// opaque zero: compiler cannot prove it's 0, so rep-loop loads can't hoist
__device__ __forceinline__ int opaque_zero() {
    int z = 0;
    asm volatile("" : "+v"(z));
    return z;
}

// ---------------- pass 1: per-sub-block histograms (R0 body x HREP) --------
__global__ __launch_bounds__(256) void hist_kernel(
    const float* __restrict__ key,       // [B*N2, 3]
    int* __restrict__ hists)             // [SUBS, NCELL]
{
    __shared__ int h[NCELL];
    const int k = blockIdx.x;            // sub-block id 0..127
    const int t = threadIdx.x;

    for (int rep = 0; rep < HREP; ++rep) {
        const int z0 = opaque_zero();
        __syncthreads();
        if (t < NCELL) h[t] = 0;
        __syncthreads();
        const int p = k * 256 + t + z0;  // global key id
        const float x = key[p * 3 + 0];
        const float y = key[p * 3 + 1];
        const float z = key[p * 3 + 2];
        const int cell = (cell_of(x) * GC + cell_of(y)) * GC + cell_of(z);
        atomicAdd(&h[cell], 1);
        __syncthreads();
        if (t < NCELL) hists[k * NCELL + t + z0] = h[t];
    }
}

// ---------------- pass 2: scan + deterministic scatter (R0 body x SREP) ----
__global__ __launch_bounds__(256) void scatter_kernel(
    const float* __restrict__ key,       // [B*N2, 3]
    const int* __restrict__ hists,       // [SUBS, NCELL]
    int* __restrict__ cell_start,        // [B, NCELL+1]
    float4* __restrict__ sorted)         // [B*N2]
{
    __shared__ int sbuf[128];
    __shared__ int cursor[NCELL];

    const int k = blockIdx.x;            // sub-block id 0..127
    const int b = k >> 5;                // batch
    const int s = k & 31;                // sub index within batch
    const int t = threadIdx.x;

    for (int rep = 0; rep < SREP; ++rep) {
        const int z0 = opaque_zero();

        int mybase = 0, total = 0;
        if (t < NCELL) {
            const int* hb = hists + (b * SUBS_PER_B) * NCELL + t + z0;
            int acc = 0;
            #pragma unroll
            for (int s2 = 0; s2 < SUBS_PER_B; ++s2) {
                if (s2 == s) mybase = acc;
                acc += hb[s2 * NCELL];
            }
            total = acc;
        }

        if (t < 128) sbuf[t] = (t < NCELL) ? total : 0;
        __syncthreads();
        for (int off = 1; off < 128; off <<= 1) {
            int v = 0;
            if (t < 128 && t >= off) v = sbuf[t - off];
            __syncthreads();
            if (t < 128) sbuf[t] += v;
            __syncthreads();
        }
        if (t < NCELL) {
            const int excl = sbuf[t] - total;
            cursor[t] = excl + mybase;
            if (s == 0) {
                cell_start[b * (NCELL + 1) + t + 1] = sbuf[t];
                if (t == 0) cell_start[b * (NCELL + 1)] = 0;
            }
        }
        __syncthreads();

        const int p = k * 256 + t + z0;
        const float x = key[p * 3 + 0];
        const float y = key[p * 3 + 1];
        const float z = key[p * 3 + 2];
        const int cell = (cell_of(x) * GC + cell_of(y)) * GC + cell_of(z);
        const int pos  = atomicAdd(&cursor[cell], 1);
        float4 v;
        v.x = x; v.y = y; v.z = z; v.w = __int_as_float(p & (N2 - 1));
        sorted[(size_t)b * N2 + pos] = v;
        // __syncthreads at next rep's scan orders this store (vmcnt drain).
    }
}

// ---------------- pass 3: per-query grid scan (R0 body x QREP) -------------
__global__ __launch_bounds__(256) void ballquery_grid_kernel(
    const float* __restrict__ query,        // [B*N1, 3]
    const float4* __restrict__ sorted,      // [B*N2] grouped by cell
    const int* __restrict__ cell_start,     // [B, 126]
    int* __restrict__ out)                  // [B*N1, K]
{
    __shared__ unsigned int bm[4 * 256];    // 4 waves x 8192-bit bitmap

    const int lane = threadIdx.x & 63;
    const int wv   = threadIdx.x >> 6;
    const int q    = blockIdx.x * 4 + wv;   // 0 .. B*N1-1
    const int b    = q >> 11;

    for (int rep = 0; rep < QREP; ++rep) {
        const int z0 = opaque_zero();

        const float qx = query[(q + z0) * 3 + 0];
        const float qy = query[(q + z0) * 3 + 1];
        const float qz = query[(q + z0) * 3 + 2];

        const float ux = qx * INVCELL, uy = qy * INVCELL, uz = qz * INVCELL;
        const int cx = cell_of(qx), cy = cell_of(qy), cz = cell_of(qz);
        const int nx = (ux - cx < 0.5f) ? cx - 1 : cx + 1;
        const int ny = (uy - cy < 0.5f) ? cy - 1 : cy + 1;
        const int nz = (uz - cz < 0.5f) ? cz - 1 : cz + 1;
        const int xlo = max(0, min(cx, nx)), xhi = min(GC - 1, max(cx, nx));
        const int ylo = max(0, min(cy, ny)), yhi = min(GC - 1, max(cy, ny));
        const int zlo = max(0, min(cz, nz)), zhi = min(GC - 1, max(cz, nz));

        unsigned int* wbm = bm + wv * 256;
        uint4 zz; zz.x = zz.y = zz.z = zz.w = 0u;
        ((uint4*)wbm)[lane] = zz;               // clear bitmap

        const int*    cs = cell_start + b * (NCELL + 1) + z0;
        const float4* sb = sorted + (size_t)b * N2 + z0;

        for (int xx = xlo; xx <= xhi; ++xx) {
            for (int yy = ylo; yy <= yhi; ++yy) {
                const int colz = (xx * GC + yy) * GC;
                const int s = cs[colz + zlo];
                const int e = cs[colz + zhi + 1];
                for (int t0 = s; t0 < e; t0 += 64) {
                    const int i = t0 + lane;
                    const float4 kv = sb[min(i, e - 1)];
                    const float dx = kv.x - qx;
                    const float dy = kv.y - qy;
                    const float dz = kv.z - qz;
                    const bool within = (i < e) && (dx * dx + dy * dy + dz * dz < R2);
                    if (within) {
                        const int id = __float_as_int(kv.w);
                        atomicOr(&wbm[id >> 5], 1u << (id & 31));
                    }
                }
            }
        }

        const uint4 w = ((const uint4*)wbm)[lane];
        const int c = __popc(w.x) + __popc(w.y) + __popc(w.z) + __popc(w.w);

        int x = c;
        #pragma unroll
        for (int off = 1; off < 64; off <<= 1) {
            int y = __shfl_up(x, off);
            if (lane >= off) x += y;
        }
        const int base = x - c;
        const int cnt  = __shfl(x, 63);

        int fs;
        if      (w.x) fs = __builtin_ctz(w.x);
        else if (w.y) fs = 32 + __builtin_ctz(w.y);
        else if (w.z) fs = 64 + __builtin_ctz(w.z);
        else if (w.w) fs = 96 + __builtin_ctz(w.w);
        else          fs = 0;
        int myfirst = c ? (lane << 7) + fs : 0x7fffffff;
        #pragma unroll
        for (int off = 32; off; off >>= 1)
            myfirst = min(myfirst, __shfl_xor(myfirst, off));
        const int firstIdx = (cnt == 0) ? 0 : myfirst;

        int* op = out + q * K;
        int slot = base;
        unsigned int wr[4] = {w.x, w.y, w.z, w.w};
        #pragma unroll
        for (int r = 0; r < 4; ++r) {
            unsigned int m = wr[r];
            const int bb = (lane << 7) + (r << 5);
            while (m) {
                const int bp = __builtin_ctz(m);
                m &= m - 1;
                if (slot < K) op[slot] = bb + bp;
                ++slot;
            }
        }

        const int kpad = cnt < K ? cnt : K;
        const int s2 = kpad + lane;
        if (s2 < K) op[s2] = firstIdx;
    }
}

// ---------------- fallback (ws too small): brute force (R4-verified) -------
__global__ __launch_bounds__(256) void bq_brute2_kernel(
    const float* __restrict__ query, const float* __restrict__ key,
    int* __restrict__ out)
{
    const int lane = threadIdx.x & 63;
    const int w    = blockIdx.x * 4 + (threadIdx.x >> 6);
    const int q0   = w * 2;
    const int q1   = q0 + 1;
    const int b    = q0 >> 11;

    const float qx0 = query[q0 * 3 + 0], qy0 = query[q0 * 3 + 1], qz0 = query[q0 * 3 + 2];
    const float qx1 = query[q1 * 3 + 0], qy1 = query[q1 * 3 + 1], qz1 = query[q1 * 3 + 2];

    const float* kb = key + (size_t)b * N2 * 3;
    const unsigned long long below = (lane == 0) ? 0ull : (~0ull >> (64 - lane));

    int cnt0 = 0, cnt1 = 0, f0 = -1, f1 = -1;
    int* op0 = out + (size_t)q0 * K;
    int* op1 = out + (size_t)q1 * K;

    #pragma unroll 4
    for (int c = 0; c < N2 / 64; ++c) {
        const int j = (c << 6) + lane;
        const float x = kb[j * 3 + 0];
        const float y = kb[j * 3 + 1];
        const float z = kb[j * 3 + 2];
        {
            const float dx = x - qx0, dy = y - qy0, dz = z - qz0;
            const bool within = dx * dx + dy * dy + dz * dz < R2;
            const unsigned long long m = __ballot(within);
            if (m) {
                if (f0 < 0) f0 = (c << 6) + __builtin_ctzll(m);
                if (within) {
                    const int slot = cnt0 + __popcll(m & below);
                    if (slot < K) op0[slot] = j;
                }
                cnt0 += __popcll(m);
            }
        }
        {
            const float dx = x - qx1, dy = y - qy1, dz = z - qz1;
            const bool within = dx * dx + dy * dy + dz * dz < R2;
            const unsigned long long m = __ballot(within);
            if (m) {
                if (f1 < 0) f1 = (c << 6) + __builtin_ctzll(m);
                if (within) {
                    const int slot = cnt1 + __popcll(m & below);
                    if (slot < K) op1[slot] = j;
                }
                cnt1 += __popcll(m);
            }
        }
    }

    const int first0 = (f0 < 0) ? 0 : f0;
    const int first1 = (f1 < 0) ? 0 : f1;
    const int c0 = cnt0 < K ? cnt0 : K;
    const int c1 = cnt1 < K ? cnt1 : K;
    if (c0 + lane < K) op0[c0 + lane] = first0;
    if (c1 + lane < K) op1[c1 + lane] = first1;
}

extern "C" void kernel_launch(void* const* d_in, const int* in_sizes, int n_in,
                              void* d_out, int out_size, void* d_ws, size_t ws_size,
                              hipStream_t stream) {
    const float* query = (const float*)d_in[0];   // B*N1*3 floats
    const float* key   = (const float*)d_in[1];   // B*N2*3 floats
    int* out = (int*)d_out;                       // B*N1*K int32

    if (ws_size < WS_NEEDED) {
        bq_brute2_kernel<<<(B * N1) / 8, 256, 0, stream>>>(query, key, out);
        return;
    }

    float4* sorted     = (float4*)d_ws;
    int*    cell_start = (int*)((char*)d_ws + SORTED_BYTES);
    int*    hists      = (int*)((char*)d_ws + SORTED_BYTES + CS_BYTES);

    hist_kernel<<<SUBS, 256, 0, stream>>>(key, hists);
    scatter_kernel<<<SUBS, 256, 0, stream>>>(key, hists, cell_start, sorted);
    ballquery_grid_kernel<<<(B * N1) / 4, 256, 0, stream>>>(query, sorted, cell_start, out);
}

// Round 8
// 98.901 us; speedup vs baseline: 1.7748x; 1.7748x over previous
//
#include <hip/hip_runtime.h>

// Ball query, single-dispatch bitmap brute force. B=4, N1=2048 queries,
// N2=8192 keys, K=64, r=0.1.
//
// R8 rationale. R7's rep-loop diagnostic finally measured the pieces:
//   query kernel Q=7.9us, hist H~0.5us, scatter S~1.0us, fill+fixed=44.2us
//   => R0's 68.2 = 44.2 + 9.4 kernels + ~14.6us of graph-node boundaries.
// Boundaries are the fat, and every multi-node/cross-block-sync variant
// lost (R1 +8, R2 +232, R3 +11, R5/R6 +4..6). R4 already proved the only
// boundary-free structure (brute force, no build) but its kernel ran 52us:
// ~245cy critical path per 64-key chunk = L2 latency fully exposed, because
// the per-chunk ballot->popcll->conditional-global-store chain serialized
// the loop and blocked load pipelining.
// R8 keeps R4's structure but removes that chain: hits only set bits in a
// wave-private 8192-bit LDS bitmap (same trick as the verified grid-query
// kernel), so the 128-iter loop body is {3 coalesced loads, 2 distance
// tests, rare LDS atomicOr} with no global stores -> loads pipeline under
// #pragma unroll. Ordered first-K output + first-hit padding come from the
// verified bitmap-extraction epilogue (exact original-index order by
// construction, even when >K hits).
//   - 1024 blocks x 256 thr; wave = 2 queries; 16 waves/CU.
//   - LDS 8KB/block: 4 waves x 2 bitmaps x 1KB.
//   - key batch 96KB, L2-resident; no workspace use at all.
// Prediction: kernel 12-18us, dur_us ~56-63 (R0=68.2). If >68.2: revert R0,
// declare structural floor (fill 40us at 84% HBM peak + fixed + ~24us).

constexpr int   K  = 64;
constexpr float R2 = 0.01f;   // 0.1^2
constexpr int   B  = 4;
constexpr int   N1 = 2048;
constexpr int   N2 = 8192;

__global__ __launch_bounds__(256) void bq_bitmap_brute_kernel(
    const float* __restrict__ query,     // [B*N1, 3]
    const float* __restrict__ key,       // [B*N2, 3]
    int* __restrict__ out)               // [B*N1, K]
{
    __shared__ unsigned int bm[8 * 256]; // 4 waves x 2 queries x 8192 bits

    const int lane = threadIdx.x & 63;
    const int wv   = threadIdx.x >> 6;
    const int w    = blockIdx.x * 4 + wv;   // wave id 0..4095
    const int q0   = w * 2;              // even => q0,q1 in same batch
    const int q1   = q0 + 1;
    const int b    = q0 >> 11;

    const float qx0 = query[q0 * 3 + 0];
    const float qy0 = query[q0 * 3 + 1];
    const float qz0 = query[q0 * 3 + 2];
    const float qx1 = query[q1 * 3 + 0];
    const float qy1 = query[q1 * 3 + 1];
    const float qz1 = query[q1 * 3 + 2];

    unsigned int* bm0 = bm + (wv * 2 + 0) * 256;
    unsigned int* bm1 = bm + (wv * 2 + 1) * 256;
    uint4 zz; zz.x = zz.y = zz.z = zz.w = 0u;
    ((uint4*)bm0)[lane] = zz;            // clear: 64 lanes x 16B = 1KB each
    ((uint4*)bm1)[lane] = zz;

    const float* kb = key + (size_t)b * N2 * 3;

    // Pure loop body: loads + VALU + rare LDS atomicOr. No ballots, no
    // global stores -> compiler can keep several chunk-loads in flight.
    #pragma unroll 4
    for (int c = 0; c < N2 / 64; ++c) {
        const int j = (c << 6) + lane;
        const float x = kb[j * 3 + 0];
        const float y = kb[j * 3 + 1];
        const float z = kb[j * 3 + 2];

        const float dx0 = x - qx0, dy0 = y - qy0, dz0 = z - qz0;
        const float dx1 = x - qx1, dy1 = y - qy1, dz1 = z - qz1;
        const float d0 = dx0 * dx0 + dy0 * dy0 + dz0 * dz0;
        const float d1 = dx1 * dx1 + dy1 * dy1 + dz1 * dz1;
        if (d0 < R2) atomicOr(&bm0[j >> 5], 1u << (j & 31));
        if (d1 < R2) atomicOr(&bm1[j >> 5], 1u << (j & 31));
    }

    // ---- extraction x2 (verified R0 epilogue): lane owns original-index
    //      range [128*lane, 128*lane+128); emit set bits in order; pad with
    //      first set bit overall (0 if none).
    #pragma unroll
    for (int g = 0; g < 2; ++g) {
        const unsigned int* wbm = g ? bm1 : bm0;
        int* op = out + (size_t)(g ? q1 : q0) * K;

        const uint4 w4 = ((const uint4*)wbm)[lane];
        const int c = __popc(w4.x) + __popc(w4.y) + __popc(w4.z) + __popc(w4.w);

        // inclusive wave prefix sum of c
        int x = c;
        #pragma unroll
        for (int off = 1; off < 64; off <<= 1) {
            int y = __shfl_up(x, off);
            if (lane >= off) x += y;
        }
        const int base = x - c;
        const int cnt  = __shfl(x, 63);

        // first set bit overall (0 if none)
        int fs;
        if      (w4.x) fs = __builtin_ctz(w4.x);
        else if (w4.y) fs = 32 + __builtin_ctz(w4.y);
        else if (w4.z) fs = 64 + __builtin_ctz(w4.z);
        else if (w4.w) fs = 96 + __builtin_ctz(w4.w);
        else           fs = 0;
        int myfirst = c ? (lane << 7) + fs : 0x7fffffff;
        #pragma unroll
        for (int off = 32; off; off >>= 1)
            myfirst = min(myfirst, __shfl_xor(myfirst, off));
        const int firstIdx = (cnt == 0) ? 0 : myfirst;

        // emit set bits in order
        int slot = base;
        unsigned int wr[4] = {w4.x, w4.y, w4.z, w4.w};
        #pragma unroll
        for (int r = 0; r < 4; ++r) {
            unsigned int m = wr[r];
            const int bb = (lane << 7) + (r << 5);
            while (m) {
                const int bp = __builtin_ctz(m);
                m &= m - 1;
                if (slot < K) op[slot] = bb + bp;
                ++slot;
            }
        }

        // pad remaining slots with firstIdx
        const int kpad = cnt < K ? cnt : K;
        const int s2 = kpad + lane;
        if (s2 < K) op[s2] = firstIdx;
    }
}

extern "C" void kernel_launch(void* const* d_in, const int* in_sizes, int n_in,
                              void* d_out, int out_size, void* d_ws, size_t ws_size,
                              hipStream_t stream) {
    const float* query = (const float*)d_in[0];   // B*N1*3 floats
    const float* key   = (const float*)d_in[1];   // B*N2*3 floats
    int* out = (int*)d_out;                       // B*N1*K int32
    (void)d_ws; (void)ws_size;                    // no workspace needed

    // 8192 queries / (4 waves x 2 queries) per 256-thread block.
    bq_bitmap_brute_kernel<<<(B * N1) / 8, 256, 0, stream>>>(query, key, out);
}